// Round 10
// baseline (105.799 us; speedup 1.0000x reference)
//
#include <hip/hip_runtime.h>
#include <math.h>

// Hausdorff distance, B=16, N=4096, D=3, fp32.
// out[b] = 0.5*(max_gt min_pred d + max_pred min_gt d), d = ||p-q||^2
//
// R10 = R9 + ILP: R9's counters (MfmaUtil 15.6% x 42us == 6.6us == the
// computed MFMA pipe time) proved the MFMA path works but each tile's
// ds_read->mfma->16 min chain is latency-exposed at 2.7 waves/SIMD.
// Fix: 64 homes per wave = TWO independent MFMA streams (afrag0/afrag1)
// sharing one bfrag read:
//   - ds_read count halves (LDS pipe 10.2 -> 5.1us)
//   - stream1's MFMA issues while stream0's mins run (intra-wave overlap)
//   - SPLIT=8 (OPP=512, LDS ~17.4KB) -> 4 blocks/CU at ~75 VGPR.
// Floors: MFMA 6.7us, min-VALU 6.8us, LDS 5.1us -> overlapped ~12us+.
//
// Formulation (v_mfma_f32_32x32x16_f16): d(m,n)=hg[m]+(hp[n]-2g_m.p_n),
// f16 hi/lo split: k0..2 (-2g_hi)(p_hi), k3..5 (-2g_hi)(p_lo),
// k6..8 (-2g_lo)(p_hi), k9..10 1*hp_{hi,lo}; hg added in fp32 at end.
// A[m][k=8*(lane>>5)+j]=afrag[j]; B same with n; C/D (m74/m101):
// col=lane&31, row=(reg&3)+8*(reg>>2)+4*(lane>>5).

#define NPTS 4096
#define NB 16
#define TPB 256
#define WAVES 4
#define HPW 64                    // homes per wave (2 MFMA streams)
#define HPB (WAVES * HPW)         // 256 homes per block
#define NHB (NPTS / HPB)          // 16 home blocks
#define SPLIT 8
#define OPP (NPTS / SPLIT)        // 512 opponents staged per block
#define TILES (OPP / 32)          // 16 bfrag tiles per wave

#define WSMIN_N (2 * NB * NPTS)

typedef _Float16 h8 __attribute__((ext_vector_type(8)));
typedef float f16v __attribute__((ext_vector_type(16)));

__global__ __launch_bounds__(TPB) void haus_scan_kernel(
        const float* __restrict__ preds, const float* __restrict__ gts,
        unsigned int* __restrict__ wsmin) {
    const int hb  = blockIdx.x & (NHB - 1);
    const int sp  = blockIdx.x >> 4;          // NHB == 16
    const int b   = blockIdx.y;
    const int dir = blockIdx.z;               // 0: home=gts vs preds; 1: home=preds vs gts
    const int t   = threadIdx.x;
    const int lane = t & 63, w = t >> 6;
    const int l31 = lane & 31, half = lane >> 5;

    const float* home = (dir == 0) ? gts : preds;
    const float* opp  = (dir == 0) ? preds : gts;
    const float* hbp = home + (size_t)b * NPTS * 3;
    const float* obp = opp  + (size_t)b * NPTS * 3;

    __shared__ h8 srec[2 * OPP];              // [khalf][point] B-form records
    __shared__ float shg[WAVES][HPW];

    // ---- stage opponents: B-form hi/lo records (full |p|^2) ----
    for (int i = 0; i < OPP / TPB; ++i) {
        int p = i * TPB + t;
        const float* s = obp + (size_t)(sp * OPP + p) * 3;
        float x = s[0], y = s[1], z = s[2];
        float hp = fmaf(x, x, fmaf(y, y, z * z));
        _Float16 xh = (_Float16)x, yh = (_Float16)y, zh = (_Float16)z;
        _Float16 xl = (_Float16)(x - (float)xh);
        _Float16 yl = (_Float16)(y - (float)yh);
        _Float16 zl = (_Float16)(z - (float)zh);
        _Float16 hph = (_Float16)hp, hpl = (_Float16)(hp - (float)hph);
        h8 lo, hi;
        lo[0] = xh; lo[1] = yh; lo[2] = zh;       // k0..2: p_hi
        lo[3] = xl; lo[4] = yl; lo[5] = zl;       // k3..5: p_lo
        lo[6] = xh; lo[7] = yh;                   // k6..7: p_hi (x,y)
        hi[0] = zh;                               // k8: p_hi z
        hi[1] = hph; hi[2] = hpl;                 // k9..10: hp split
        hi[3] = (_Float16)0; hi[4] = (_Float16)0;
        hi[5] = (_Float16)0; hi[6] = (_Float16)0; hi[7] = (_Float16)0;
        srec[p] = lo;
        srec[OPP + p] = hi;
    }

    // ---- A-frags: two streams of 32 homes, -2 * hi/lo split ----
    h8 afrag[2];
    {
#pragma unroll
        for (int a = 0; a < 2; ++a) {
            int m = hb * HPB + w * HPW + a * 32 + l31;
            float gx = hbp[m * 3 + 0], gy = hbp[m * 3 + 1], gz = hbp[m * 3 + 2];
            float hg = fmaf(gx, gx, fmaf(gy, gy, gz * gz));
            shg[w][a * 32 + l31] = hg;        // both lane-halves write same value
            _Float16 gxh = (_Float16)gx, gyh = (_Float16)gy, gzh = (_Float16)gz;
            _Float16 gxl = (_Float16)(gx - (float)gxh);
            _Float16 gyl = (_Float16)(gy - (float)gyh);
            _Float16 gzl = (_Float16)(gz - (float)gzh);
            const _Float16 n2 = (_Float16)(-2.0f);
            h8 f;
            if (half == 0) {                  // k0..7
                f[0] = n2 * gxh; f[1] = n2 * gyh; f[2] = n2 * gzh;
                f[3] = n2 * gxh; f[4] = n2 * gyh; f[5] = n2 * gzh;
                f[6] = n2 * gxl; f[7] = n2 * gyl;
            } else {                          // k8..15
                f[0] = n2 * gzl;
                f[1] = (_Float16)1; f[2] = (_Float16)1;
                f[3] = (_Float16)0; f[4] = (_Float16)0;
                f[5] = (_Float16)0; f[6] = (_Float16)0; f[7] = (_Float16)0;
            }
            afrag[a] = f;
        }
    }

    f16v zc = {};                             // zero C
    float best0[16], best1[16];
#pragma unroll
    for (int r = 0; r < 16; ++r) { best0[r] = INFINITY; best1[r] = INFINITY; }

    __syncthreads();

    const int base = half * OPP + l31;        // srec index for this lane
#pragma unroll 2
    for (int tt = 0; tt < TILES; ++tt) {
        h8 bfrag = srec[base + tt * 32];      // one ds_read_b128, conflict-free
        f16v D0 = __builtin_amdgcn_mfma_f32_32x32x16_f16(afrag[0], bfrag, zc, 0, 0, 0);
        f16v D1 = __builtin_amdgcn_mfma_f32_32x32x16_f16(afrag[1], bfrag, zc, 0, 0, 0);
#pragma unroll
        for (int r = 0; r < 16; ++r) best0[r] = fminf(best0[r], D0[r]);
#pragma unroll
        for (int r = 0; r < 16; ++r) best1[r] = fminf(best1[r], D1[r]);
    }

    // ---- min over 32 cols: butterfly within each 32-lane half ----
#pragma unroll
    for (int off = 16; off >= 1; off >>= 1) {
#pragma unroll
        for (int r = 0; r < 16; ++r) {
            best0[r] = fminf(best0[r], __shfl_xor(best0[r], off, 64));
            best1[r] = fminf(best1[r], __shfl_xor(best1[r], off, 64));
        }
    }

    unsigned int* slot = wsmin + ((size_t)dir * NB + b) * NPTS + hb * HPB + w * HPW;
    if (l31 == 0) {                           // lanes 0 and 32: disjoint row sets
#pragma unroll
        for (int r = 0; r < 16; ++r) {
            int row = (r & 3) + 8 * (r >> 2) + 4 * half;
            float d0 = fmaxf(best0[r] + shg[w][row], 0.0f);
            float d1 = fmaxf(best1[r] + shg[w][32 + row], 0.0f);
            atomicMin(slot + row, __float_as_uint(d0));
            atomicMin(slot + 32 + row, __float_as_uint(d1));
        }
    }
}

__global__ __launch_bounds__(TPB) void haus_final_kernel(
        const unsigned int* __restrict__ wsmin, float* __restrict__ out) {
    const int b = blockIdx.x;
    const int t = threadIdx.x;
    const float4* w0 = (const float4*)(wsmin + ((size_t)0 * NB + b) * NPTS);
    const float4* w1 = (const float4*)(wsmin + ((size_t)1 * NB + b) * NPTS);
    float m1 = -INFINITY, m2 = -INFINITY;
#pragma unroll
    for (int r = 0; r < NPTS / 4 / TPB; ++r) {   // 4 float4 per thread
        float4 a = w0[r * TPB + t];
        float4 c = w1[r * TPB + t];
        m1 = fmaxf(fmaxf(fmaxf(a.x, a.y), fmaxf(a.z, a.w)), m1);
        m2 = fmaxf(fmaxf(fmaxf(c.x, c.y), fmaxf(c.z, c.w)), m2);
    }
#pragma unroll
    for (int off = 32; off > 0; off >>= 1) {
        m1 = fmaxf(m1, __shfl_down(m1, off, 64));
        m2 = fmaxf(m2, __shfl_down(m2, off, 64));
    }
    __shared__ float s1[4], s2[4];
    if ((t & 63) == 0) { s1[t >> 6] = m1; s2[t >> 6] = m2; }
    __syncthreads();
    if (t == 0) {
        float a = fmaxf(fmaxf(s1[0], s1[1]), fmaxf(s1[2], s1[3]));
        float c = fmaxf(fmaxf(s2[0], s2[1]), fmaxf(s2[2], s2[3]));
        out[b] = 0.5f * (a + c);              // wsmin holds full d
    }
}

extern "C" void kernel_launch(void* const* d_in, const int* in_sizes, int n_in,
                              void* d_out, int out_size, void* d_ws, size_t ws_size,
                              hipStream_t stream) {
    const float* preds = (const float*)d_in[0];
    const float* gts   = (const float*)d_in[1];
    float* out = (float*)d_out;
    unsigned int* wsmin = (unsigned int*)d_ws;   // 512 KB used

    // 0xFF fill = +inf sentinel for uint atomicMin (all finite d bits smaller)
    hipMemsetAsync(wsmin, 0xFF, (size_t)WSMIN_N * sizeof(unsigned int), stream);

    haus_scan_kernel<<<dim3(NHB * SPLIT, NB, 2), dim3(TPB), 0, stream>>>(
        preds, gts, wsmin);

    haus_final_kernel<<<dim3(NB), dim3(TPB), 0, stream>>>(wsmin, out);
}

// Round 11
// 89.802 us; speedup vs baseline: 1.1781x; 1.1781x over previous
//
#include <hip/hip_runtime.h>
#include <math.h>

// Hausdorff distance, B=16, N=4096, D=3, fp32.
// out[b] = 0.5*(max_gt min_pred d + max_pred min_gt d), d = ||p-q||^2
//
// R11: LDS-pipe relief. R10 post-mortem: the col-min butterfly's
// __shfl_xor ops are ds_swizzle/bpermute on the LDS pipe (~5.8cyc);
// R9 = 1.31M, R10 = 2.62M of them -> 12/24us of LDS issue, the true
// critical pipe (ds_read was only 10.2/5.1us).
//  - steps xor{1,2,4,8} -> v_min + update_dpp(row_ror:n): VALU pipe,
//    ZERO LDS. (rotation-reduce within 16-lane DPP rows == min over
//    cols 0..15 / 16..31); only the 16-lane-cross step remains on LDS
//    (one ds_swizzle 0x401F per reg).
//  - SPLIT=2, HPW=64 (2 MFMA streams/wave): waves 16384 -> 4096;
//    ds_read halves again; atomics halve vs R9. LDS 65KB -> 2 blocks/CU;
//    intra-wave 2-stream ILP covers the lower occupancy.
// Budget: LDS 7.4us, VALU ~11us, MFMA 6.7us -> overlapped 15-20us.
//
// Formulation (v_mfma_f32_32x32x16_f16): d(m,n)=hg[m]+(hp[n]-2g_m.p_n),
// f16 hi/lo split: k0..2 (-2g_hi)(p_hi), k3..5 (-2g_hi)(p_lo),
// k6..8 (-2g_lo)(p_hi), k9..10 1*hp_{hi,lo}; hg added in fp32 at end.
// C/D (m74/m101, R9/R10-validated): col=lane&31,
// row=(reg&3)+8*(reg>>2)+4*(lane>>5).

#define NPTS 4096
#define NB 16
#define TPB 256
#define WAVES 4
#define HPW 64                    // homes per wave (2 MFMA streams)
#define HPB (WAVES * HPW)         // 256 homes per block
#define NHB (NPTS / HPB)          // 16 home blocks
#define SPLIT 2
#define OPP (NPTS / SPLIT)        // 2048 opponents staged per block
#define TILES (OPP / 32)          // 64 bfrag tiles per wave

#define WSMIN_N (2 * NB * NPTS)

typedef _Float16 h8 __attribute__((ext_vector_type(8)));
typedef float f16v __attribute__((ext_vector_type(16)));

// min with DPP row_ror:N (VALU pipe; rows of 16 lanes, cyclic rotate)
template <int CTRL>
__device__ __forceinline__ float min_dpp(float v) {
    int s = __builtin_amdgcn_update_dpp(0, __float_as_int(v), CTRL, 0xF, 0xF, true);
    return fminf(v, __int_as_float(s));
}

__global__ __launch_bounds__(TPB) void haus_scan_kernel(
        const float* __restrict__ preds, const float* __restrict__ gts,
        unsigned int* __restrict__ wsmin) {
    const int hb  = blockIdx.x & (NHB - 1);
    const int sp  = blockIdx.x >> 4;          // NHB == 16
    const int b   = blockIdx.y;
    const int dir = blockIdx.z;               // 0: home=gts vs preds; 1: home=preds vs gts
    const int t   = threadIdx.x;
    const int lane = t & 63, w = t >> 6;
    const int l31 = lane & 31, half = lane >> 5;

    const float* home = (dir == 0) ? gts : preds;
    const float* opp  = (dir == 0) ? preds : gts;
    const float* hbp = home + (size_t)b * NPTS * 3;
    const float* obp = opp  + (size_t)b * NPTS * 3;

    __shared__ h8 srec[2 * OPP];              // [khalf][point] B-form records (64KB)
    __shared__ float shg[WAVES][HPW];

    // ---- stage opponents: B-form hi/lo records (full |p|^2) ----
    for (int i = 0; i < OPP / TPB; ++i) {
        int p = i * TPB + t;
        const float* s = obp + (size_t)(sp * OPP + p) * 3;
        float x = s[0], y = s[1], z = s[2];
        float hp = fmaf(x, x, fmaf(y, y, z * z));
        _Float16 xh = (_Float16)x, yh = (_Float16)y, zh = (_Float16)z;
        _Float16 xl = (_Float16)(x - (float)xh);
        _Float16 yl = (_Float16)(y - (float)yh);
        _Float16 zl = (_Float16)(z - (float)zh);
        _Float16 hph = (_Float16)hp, hpl = (_Float16)(hp - (float)hph);
        h8 lo, hi;
        lo[0] = xh; lo[1] = yh; lo[2] = zh;       // k0..2: p_hi
        lo[3] = xl; lo[4] = yl; lo[5] = zl;       // k3..5: p_lo
        lo[6] = xh; lo[7] = yh;                   // k6..7: p_hi (x,y)
        hi[0] = zh;                               // k8: p_hi z
        hi[1] = hph; hi[2] = hpl;                 // k9..10: hp split
        hi[3] = (_Float16)0; hi[4] = (_Float16)0;
        hi[5] = (_Float16)0; hi[6] = (_Float16)0; hi[7] = (_Float16)0;
        srec[p] = lo;
        srec[OPP + p] = hi;
    }

    // ---- A-frags: two streams of 32 homes, -2 * hi/lo split ----
    h8 afrag[2];
#pragma unroll
    for (int a = 0; a < 2; ++a) {
        int m = hb * HPB + w * HPW + a * 32 + l31;
        float gx = hbp[m * 3 + 0], gy = hbp[m * 3 + 1], gz = hbp[m * 3 + 2];
        float hg = fmaf(gx, gx, fmaf(gy, gy, gz * gz));
        shg[w][a * 32 + l31] = hg;            // both lane-halves write same value
        _Float16 gxh = (_Float16)gx, gyh = (_Float16)gy, gzh = (_Float16)gz;
        _Float16 gxl = (_Float16)(gx - (float)gxh);
        _Float16 gyl = (_Float16)(gy - (float)gyh);
        _Float16 gzl = (_Float16)(gz - (float)gzh);
        const _Float16 n2 = (_Float16)(-2.0f);
        h8 f;
        if (half == 0) {                      // k0..7
            f[0] = n2 * gxh; f[1] = n2 * gyh; f[2] = n2 * gzh;
            f[3] = n2 * gxh; f[4] = n2 * gyh; f[5] = n2 * gzh;
            f[6] = n2 * gxl; f[7] = n2 * gyl;
        } else {                              // k8..15
            f[0] = n2 * gzl;
            f[1] = (_Float16)1; f[2] = (_Float16)1;
            f[3] = (_Float16)0; f[4] = (_Float16)0;
            f[5] = (_Float16)0; f[6] = (_Float16)0; f[7] = (_Float16)0;
        }
        afrag[a] = f;
    }

    f16v zc = {};                             // zero C
    float best0[16], best1[16];
#pragma unroll
    for (int r = 0; r < 16; ++r) { best0[r] = INFINITY; best1[r] = INFINITY; }

    __syncthreads();

    const int base = half * OPP + l31;        // srec index for this lane
#pragma unroll 2
    for (int tt = 0; tt < TILES; ++tt) {
        h8 bfrag = srec[base + tt * 32];      // one ds_read_b128 per 2 MFMAs
        f16v D0 = __builtin_amdgcn_mfma_f32_32x32x16_f16(afrag[0], bfrag, zc, 0, 0, 0);
        f16v D1 = __builtin_amdgcn_mfma_f32_32x32x16_f16(afrag[1], bfrag, zc, 0, 0, 0);
#pragma unroll
        for (int r = 0; r < 16; ++r) best0[r] = fminf(best0[r], D0[r]);
#pragma unroll
        for (int r = 0; r < 16; ++r) best1[r] = fminf(best1[r], D1[r]);
    }

    // ---- min over 32 cols ----
    // steps 1,2,4,8: DPP row_ror rotations within 16-lane rows (VALU pipe)
#pragma unroll
    for (int r = 0; r < 16; ++r) {
        float a0 = best0[r], a1 = best1[r];
        a0 = min_dpp<0x121>(a0); a1 = min_dpp<0x121>(a1);   // ror 1
        a0 = min_dpp<0x122>(a0); a1 = min_dpp<0x122>(a1);   // ror 2
        a0 = min_dpp<0x124>(a0); a1 = min_dpp<0x124>(a1);   // ror 4
        a0 = min_dpp<0x128>(a0); a1 = min_dpp<0x128>(a1);   // ror 8
        // final step: cross the two 16-lane rows within each 32-half
        // ds_swizzle BitMode xor=16, and=0x1F -> offset 0x401F
        float s0 = __int_as_float(__builtin_amdgcn_ds_swizzle(__float_as_int(a0), 0x401F));
        float s1 = __int_as_float(__builtin_amdgcn_ds_swizzle(__float_as_int(a1), 0x401F));
        best0[r] = fminf(a0, s0);
        best1[r] = fminf(a1, s1);
    }

    unsigned int* slot = wsmin + ((size_t)dir * NB + b) * NPTS + hb * HPB + w * HPW;
    if (l31 == 0) {                           // lanes 0 and 32: disjoint row sets
#pragma unroll
        for (int r = 0; r < 16; ++r) {
            int row = (r & 3) + 8 * (r >> 2) + 4 * half;
            float d0 = fmaxf(best0[r] + shg[w][row], 0.0f);
            float d1 = fmaxf(best1[r] + shg[w][32 + row], 0.0f);
            atomicMin(slot + row, __float_as_uint(d0));
            atomicMin(slot + 32 + row, __float_as_uint(d1));
        }
    }
}

__global__ __launch_bounds__(TPB) void haus_final_kernel(
        const unsigned int* __restrict__ wsmin, float* __restrict__ out) {
    const int b = blockIdx.x;
    const int t = threadIdx.x;
    const float4* w0 = (const float4*)(wsmin + ((size_t)0 * NB + b) * NPTS);
    const float4* w1 = (const float4*)(wsmin + ((size_t)1 * NB + b) * NPTS);
    float m1 = -INFINITY, m2 = -INFINITY;
#pragma unroll
    for (int r = 0; r < NPTS / 4 / TPB; ++r) {   // 4 float4 per thread
        float4 a = w0[r * TPB + t];
        float4 c = w1[r * TPB + t];
        m1 = fmaxf(fmaxf(fmaxf(a.x, a.y), fmaxf(a.z, a.w)), m1);
        m2 = fmaxf(fmaxf(fmaxf(c.x, c.y), fmaxf(c.z, c.w)), m2);
    }
#pragma unroll
    for (int off = 32; off > 0; off >>= 1) {
        m1 = fmaxf(m1, __shfl_down(m1, off, 64));
        m2 = fmaxf(m2, __shfl_down(m2, off, 64));
    }
    __shared__ float s1[4], s2[4];
    if ((t & 63) == 0) { s1[t >> 6] = m1; s2[t >> 6] = m2; }
    __syncthreads();
    if (t == 0) {
        float a = fmaxf(fmaxf(s1[0], s1[1]), fmaxf(s1[2], s1[3]));
        float c = fmaxf(fmaxf(s2[0], s2[1]), fmaxf(s2[2], s2[3]));
        out[b] = 0.5f * (a + c);              // wsmin holds full d
    }
}

extern "C" void kernel_launch(void* const* d_in, const int* in_sizes, int n_in,
                              void* d_out, int out_size, void* d_ws, size_t ws_size,
                              hipStream_t stream) {
    const float* preds = (const float*)d_in[0];
    const float* gts   = (const float*)d_in[1];
    float* out = (float*)d_out;
    unsigned int* wsmin = (unsigned int*)d_ws;   // 512 KB used

    // 0xFF fill = +inf sentinel for uint atomicMin (all finite d bits smaller)
    hipMemsetAsync(wsmin, 0xFF, (size_t)WSMIN_N * sizeof(unsigned int), stream);

    haus_scan_kernel<<<dim3(NHB * SPLIT, NB, 2), dim3(TPB), 0, stream>>>(
        preds, gts, wsmin);

    haus_final_kernel<<<dim3(NB), dim3(TPB), 0, stream>>>(wsmin, out);
}